// Round 16
// baseline (675.605 us; speedup 1.0000x reference)
//
#include <hip/hip_runtime.h>
#include <hip/hip_bf16.h>
#include <math.h>

#define B_ 256
#define T_ 256
#define HLS 128

typedef __bf16 bf16x8 __attribute__((ext_vector_type(8)));
typedef float f32x4 __attribute__((ext_vector_type(4)));
typedef unsigned int u32x4 __attribute__((ext_vector_type(4)));
typedef _Float16 f16x4 __attribute__((ext_vector_type(4)));

__device__ __forceinline__ float leakyf(float v) { return v > 0.f ? v : 0.01f * v; }
__device__ __forceinline__ float sigfast(float x) { return __builtin_amdgcn_rcpf(1.f + __expf(-x)); }
__device__ __forceinline__ float tanhfast(float x) {
    float e = __expf(2.f * x);
    return 1.f - 2.f * __builtin_amdgcn_rcpf(e + 1.f);
}
__device__ __forceinline__ unsigned short bf16bits(float v) {
    union { __hip_bfloat16 h; unsigned short u; } cv;
    cv.h = __float2bfloat16(v);
    return cv.u;
}
__device__ __forceinline__ unsigned int bfpack(float a, float b) {
    return (unsigned int)bf16bits(a) | ((unsigned int)bf16bits(b) << 16);
}
// barrier that does NOT drain vmcnt: LDS visibility only, global loads stay in flight
__device__ __forceinline__ void lds_barrier() {
    asm volatile("s_waitcnt lgkmcnt(0)" ::: "memory");
    __builtin_amdgcn_s_barrier();
}

// ---------------------------------------------------------------- merged preps + conv1 + Wd1-transpose (one dispatch)
__global__ __launch_bounds__(256) void prep_all(
    const float* __restrict__ Wh1, const float* __restrict__ Wh2,
    const float* __restrict__ Wx1, const float* __restrict__ Wx2,
    const float* __restrict__ W2,  const float* __restrict__ W3,
    const float* __restrict__ x,   const float* __restrict__ W1,
    const float* __restrict__ bc1, const float* __restrict__ Wd1,
    __hip_bfloat16* __restrict__ oh1, __hip_bfloat16* __restrict__ oh2,
    __hip_bfloat16* __restrict__ ox1, __hip_bfloat16* __restrict__ ox2,
    __hip_bfloat16* __restrict__ oW2, __hip_bfloat16* __restrict__ oW3,
    __hip_bfloat16* __restrict__ a1out, __hip_bfloat16* __restrict__ WdT)
{
    __shared__ float tileT[64][68];
    int bx = blockIdx.x;
    if (bx < 1024) {
        int which = bx >> 8;
        int idx = (bx & 255) * 256 + threadIdx.x;   // 0..65535
        int k = idx >> 9, n = idx & 511;
        const float* in = which == 0 ? Wh1 : which == 1 ? Wh2 : which == 2 ? Wx1 : Wx2;
        __hip_bfloat16* out = which == 0 ? oh1 : which == 1 ? oh2 : which == 2 ? ox1 : ox2;
        out[n * 128 + k] = __float2bfloat16(in[idx]);
    } else if (bx < 1344) {
        int idx = (bx - 1024) * 256 + threadIdx.x;  // 0..81919
        int n = idx & 511, r = idx >> 9;
        int ci = r & 31, kt = r >> 5;
        oW2[n * 160 + kt * 32 + ci] = __float2bfloat16(W2[idx]);
    } else if (bx < 2624) {
        int idx = (bx - 1344) * 256 + threadIdx.x;  // 0..327679
        int co = idx & 127, rest = idx >> 7;
        int ci = rest & 511, k = rest >> 9;
        oW3[((size_t)(k * 128 + co)) * 512 + ci] = __float2bfloat16(W3[idx]);
    } else if (bx < 10816) {
        int bb = bx - 2624;                          // 0..8191
        int tid  = threadIdx.x;
        int co   = tid & 31;
        int tsub = tid >> 5;
        int b    = bb >> 5;
        int t    = ((bb & 31) << 3) + tsub;
        float acc = bc1[co];
        #pragma unroll
        for (int k = 0; k < 5; ++k) {
            int tt = t + k - 2;
            if (tt < 0 || tt >= T_) continue;
            const float* xr = x + ((size_t)b * T_ + tt) * 8;
            #pragma unroll
            for (int ci = 0; ci < 8; ++ci)
                acc += xr[ci] * W1[(k * 8 + ci) * 32 + co];
        }
        a1out[((size_t)b * T_ + t) * 32 + co] = __float2bfloat16(leakyf(acc));
    } else {
        int tt = bx - 10816;                         // 0..4095
        int tid = threadIdx.x;
        int k0 = (tt & 511) * 64, n0 = (tt >> 9) * 64;
        #pragma unroll
        for (int it = 0; it < 4; ++it) {
            int idx = tid + it * 256;        // 0..1023
            int k = idx >> 4, nc = idx & 15;
            float4 v = *(const float4*)&Wd1[(size_t)(k0 + k) * 512 + n0 + nc * 4];
            tileT[nc * 4 + 0][k] = v.x; tileT[nc * 4 + 1][k] = v.y;
            tileT[nc * 4 + 2][k] = v.z; tileT[nc * 4 + 3][k] = v.w;
        }
        __syncthreads();
        #pragma unroll
        for (int it = 0; it < 2; ++it) {
            int idx = tid + it * 256;        // 0..511
            int n = idx >> 3, kc = idx & 7;
            const float* src = &tileT[n][kc * 8];
            float4 a = *(const float4*)src;
            float4 b = *(const float4*)(src + 4);
            u32x4 w = { bfpack(a.x, a.y), bfpack(a.z, a.w), bfpack(b.x, b.y), bfpack(b.z, b.w) };
            *(u32x4*)&WdT[(size_t)(n0 + n) * 32768 + k0 + kc * 8] = w;
        }
    }
}

// ---------------------------------------------------------------- FUSED conv2+conv3+X1, 64-row tile (25 KB LDS -> 4 blocks/CU)
// a2t plain [row][136]: odd 16B row stride (17) auto-rotates bank groups — no swizzle math.
__global__ __launch_bounds__(512) void conv23_fused(
    const __hip_bfloat16* __restrict__ a1,   // [B*T][32]
    const __hip_bfloat16* __restrict__ W2T,  // [512][160]
    const float* __restrict__ bias2,
    const __hip_bfloat16* __restrict__ W3T,  // [5][128][512]
    const float* __restrict__ bias3,
    const __hip_bfloat16* __restrict__ WxT1, // [512][128]
    const float* __restrict__ b1,
    _Float16* __restrict__ Xout)             // [B,T,128,4] fp16 gate-interleaved
{
    __shared__ __align__(16) unsigned short a1t[84 * 40];    // rows t0-4 .. t0+79
    __shared__ __align__(16) unsigned short a2t[68 * 136];   // a2 rows t0-2 .. t0+65
    const int tid = threadIdx.x, l = tid & 63, w = tid >> 6;
    const int lr = l & 15, lg = l >> 4;
    const int b  = blockIdx.x >> 2;
    const int t0 = (blockIdx.x & 3) << 6;
    const size_t bT = (size_t)b * T_;

    for (int i = tid; i < 84 * 4; i += 512) {
        int row = i >> 2, c = i & 3;
        int t = t0 - 4 + row;
        u32x4 v = {0u, 0u, 0u, 0u};
        if (t >= 0 && t < T_) v = *(const u32x4*)&a1[(bT + t) * 32 + c * 8];
        *(u32x4*)&a1t[row * 40 + c * 8] = v;
    }

    f32x4 acc3[2][2];
    #pragma unroll
    for (int fm = 0; fm < 2; ++fm)
        #pragma unroll
        for (int n = 0; n < 2; ++n) acc3[fm][n] = (f32x4){0.f, 0.f, 0.f, 0.f};

    const int tq = w >> 2, cq = w & 3;   // conv3 wave tile: rows tq*32 (+2 fm x16), cols cq*32 (+2 n x16)
    __syncthreads();

    #pragma unroll 1
    for (int cic = 0; cic < 4; ++cic) {
        // ---- conv2: wave w computes a2 column cic*128 + w*16+lr for rows L in [0,68)
        {
            const int co2 = cic * 128 + w * 16 + lr;
            bf16x8 bf2[5];
            #pragma unroll
            for (int kt = 0; kt < 5; ++kt)
                bf2[kt] = *(const bf16x8*)&W2T[(size_t)co2 * 160 + kt * 32 + lg * 8];
            const float bb2 = bias2[co2];
            const int colc = w * 16 + lr;
            #pragma unroll 1
            for (int m = 0; m < 5; ++m) {
                f32x4 a = (f32x4){0.f, 0.f, 0.f, 0.f};
                #pragma unroll
                for (int kt = 0; kt < 5; ++kt) {
                    bf16x8 af = *(const bf16x8*)&a1t[(m * 16 + lr + kt) * 40 + lg * 8];
                    a = __builtin_amdgcn_mfma_f32_16x16x32_bf16(af, bf2[kt], a, 0, 0, 0);
                }
                #pragma unroll
                for (int r = 0; r < 4; ++r) {
                    int L = m * 16 + lg * 4 + r;
                    int t = t0 - 2 + L;
                    unsigned short v = 0;
                    if (t >= 0 && t < T_) v = bf16bits(leakyf(a[r] + bb2));
                    if (L < 68)
                        a2t[L * 136 + colc] = v;
                }
            }
        }
        __syncthreads();
        // ---- conv3 partial accumulate over this ci chunk
        #pragma unroll 1
        for (int k = 0; k < 5; ++k) {
            #pragma unroll
            for (int cf = 0; cf < 4; ++cf) {
                bf16x8 af3[2];
                #pragma unroll
                for (int fm = 0; fm < 2; ++fm) {
                    int L = tq * 32 + fm * 16 + lr + k;
                    af3[fm] = *(const bf16x8*)&a2t[L * 136 + cf * 32 + lg * 8];
                }
                #pragma unroll
                for (int n = 0; n < 2; ++n) {
                    bf16x8 bf = *(const bf16x8*)&W3T[(size_t)(k * 128 + cq * 32 + n * 16 + lr) * 512
                                                     + cic * 128 + cf * 32 + lg * 8];
                    acc3[0][n] = __builtin_amdgcn_mfma_f32_16x16x32_bf16(af3[0], bf, acc3[0][n], 0, 0, 0);
                    acc3[1][n] = __builtin_amdgcn_mfma_f32_16x16x32_bf16(af3[1], bf, acc3[1][n], 0, 0, 0);
                }
            }
        }
        __syncthreads();
    }
    // ---- a3 tile (bias+leaky, bf16) into LDS (reuse a2t rows 0..63, plain layout)
    #pragma unroll
    for (int n = 0; n < 2; ++n) {
        int co = cq * 32 + n * 16 + lr;
        float bb = bias3[co];
        #pragma unroll
        for (int fm = 0; fm < 2; ++fm) {
            #pragma unroll
            for (int r = 0; r < 4; ++r) {
                int L = tq * 32 + fm * 16 + lg * 4 + r;
                a2t[L * 136 + co] = bf16bits(leakyf(acc3[fm][n][r] + bb));
            }
        }
    }
    __syncthreads();
    // ---- X1 phase: wave w -> row-tile rt = w&3 (16 rows), gate-col half ch = w>>2 (j in [ch*64, ch*64+64))
    const int rt = w & 3, ch = w >> 2;
    const int Lr = rt * 16 + lr;
    bf16x8 afx[4];
    #pragma unroll
    for (int kf = 0; kf < 4; ++kf)
        afx[kf] = *(const bf16x8*)&a2t[Lr * 136 + kf * 32 + lg * 8];
    _Float16* X16 = Xout + (bT + t0) * 512;
    {
        f32x4 acc2[4][4];
        #pragma unroll
        for (int s = 0; s < 4; ++s)
            #pragma unroll
            for (int qq = 0; qq < 4; ++qq) acc2[s][qq] = (f32x4){0.f, 0.f, 0.f, 0.f};
        #pragma unroll
        for (int s = 0; s < 4; ++s)
            #pragma unroll
            for (int qq = 0; qq < 4; ++qq) {
                int n = s * 128 + ch * 64 + qq * 16 + lr;
                #pragma unroll
                for (int kf = 0; kf < 4; ++kf) {
                    bf16x8 bf = *(const bf16x8*)&WxT1[(size_t)n * 128 + kf * 32 + lg * 8];
                    acc2[s][qq] = __builtin_amdgcn_mfma_f32_16x16x32_bf16(afx[kf], bf, acc2[s][qq], 0, 0, 0);
                }
            }
        #pragma unroll
        for (int qq = 0; qq < 4; ++qq) {
            int j = ch * 64 + qq * 16 + lr;
            float bi = b1[j], bfv = b1[j + 128], bg = b1[j + 256], bo = b1[j + 384];
            #pragma unroll
            for (int r = 0; r < 4; ++r) {
                int m = rt * 16 + lg * 4 + r;
                f16x4 v = { (_Float16)(acc2[0][qq][r] + bi), (_Float16)(acc2[1][qq][r] + bfv),
                            (_Float16)(acc2[2][qq][r] + bg), (_Float16)(acc2[3][qq][r] + bo) };
                *(f16x4*)&X16[(size_t)m * 512 + (size_t)j * 4] = v;
            }
        }
    }
}

// ---------------------------------------------------------------- X-GEMM (bf16 MFMA): X[m][j][gate] fp16 = A[M,128] @ BT[512,128]^T + b
__global__ __launch_bounds__(512) void gemm_mfma(
    const __hip_bfloat16* __restrict__ A,
    const __hip_bfloat16* __restrict__ BT,
    const float* __restrict__ bias,
    float* __restrict__ C,
    int K, int klen, int ileave)
{
    const int tid = threadIdx.x, l = tid & 63, w = tid >> 6;
    const int lr = l & 15, lg = l >> 4;
    const size_t m0 = (size_t)blockIdx.x * 128 + w * 16;
    const int k0 = blockIdx.z * klen;
    C += (size_t)blockIdx.z * gridDim.x * 128 * 512;

    f32x4 acc[32];
    #pragma unroll
    for (int q = 0; q < 32; ++q) acc[q] = (f32x4){0.f, 0.f, 0.f, 0.f};

    const __hip_bfloat16* Arow  = A + (m0 + lr) * (size_t)K + k0 + lg * 8;
    const __hip_bfloat16* Bbase = BT + (size_t)lr * K + k0 + lg * 8;

    const int nkf = klen >> 5;
    for (int kf = 0; kf < nkf; ++kf) {
        bf16x8 af = *(const bf16x8*)(Arow + kf * 32);
        #pragma unroll
        for (int q = 0; q < 32; ++q) {
            bf16x8 bf = *(const bf16x8*)(Bbase + (size_t)q * 16 * K + kf * 32);
            acc[q] = __builtin_amdgcn_mfma_f32_16x16x32_bf16(af, bf, acc[q], 0, 0, 0);
        }
    }
    if (ileave) {
        _Float16* C16 = (_Float16*)C;
        #pragma unroll
        for (int qj = 0; qj < 8; ++qj) {
            int j = qj * 16 + lr;
            float bi = bias[j], bf_ = bias[j + 128], bg = bias[j + 256], bo = bias[j + 384];
            #pragma unroll
            for (int r = 0; r < 4; ++r) {
                size_t m = m0 + lg * 4 + r;
                f16x4 v = { (_Float16)(acc[qj][r] + bi), (_Float16)(acc[qj + 8][r] + bf_),
                            (_Float16)(acc[qj + 16][r] + bg), (_Float16)(acc[qj + 24][r] + bo) };
                *(f16x4*)&C16[m * 512 + (size_t)j * 4] = v;
            }
        }
    } else {
        #pragma unroll
        for (int q = 0; q < 32; ++q) {
            int n = q * 16 + lr;
            float bb = bias ? bias[n] : 0.f;
            #pragma unroll
            for (int r = 0; r < 4; ++r) {
                size_t m = m0 + lg * 4 + r;
                C[m * 512 + n] = acc[q][r] + bb;
            }
        }
    }
}

// ---------------------------------------------------------------- dense GEMM: part[z][256][512] = out2[256,32768] @ WdT[512,32768]^T
__global__ __launch_bounds__(512) void gemm_dense(
    const __hip_bfloat16* __restrict__ A,    // [256][32768]
    const __hip_bfloat16* __restrict__ BT,   // [512][32768]
    float* __restrict__ part)                // [64][256][512]
{
    const int tid = threadIdx.x, l = tid & 63, w = tid >> 6;
    const int lr = l & 15, lg = l >> 4;
    const int nt = blockIdx.x;               // 0..3
    const int z  = blockIdx.y;               // 0..63
    const int k0 = z * 512;
    const int m0 = w * 32;

    f32x4 acc[2][8];
    #pragma unroll
    for (int fm = 0; fm < 2; ++fm)
        #pragma unroll
        for (int q = 0; q < 8; ++q) acc[fm][q] = (f32x4){0.f, 0.f, 0.f, 0.f};

    const __hip_bfloat16* Ab = A  + (size_t)(m0 + lr) * 32768 + k0 + lg * 8;
    const __hip_bfloat16* Bb = BT + (size_t)(nt * 128 + lr) * 32768 + k0 + lg * 8;

    #pragma unroll 2
    for (int kf = 0; kf < 16; ++kf) {
        bf16x8 af0 = *(const bf16x8*)(Ab + kf * 32);
        bf16x8 af1 = *(const bf16x8*)(Ab + (size_t)16 * 32768 + kf * 32);
        #pragma unroll
        for (int q = 0; q < 8; ++q) {
            bf16x8 bf = *(const bf16x8*)(Bb + (size_t)q * 16 * 32768 + kf * 32);
            acc[0][q] = __builtin_amdgcn_mfma_f32_16x16x32_bf16(af0, bf, acc[0][q], 0, 0, 0);
            acc[1][q] = __builtin_amdgcn_mfma_f32_16x16x32_bf16(af1, bf, acc[1][q], 0, 0, 0);
        }
    }
    float* Cp = part + (size_t)z * 131072;
    #pragma unroll
    for (int fm = 0; fm < 2; ++fm)
        #pragma unroll
        for (int q = 0; q < 8; ++q) {
            int n = nt * 128 + q * 16 + lr;
            #pragma unroll
            for (int r = 0; r < 4; ++r) {
                int m = m0 + fm * 16 + lg * 4 + r;
                Cp[(size_t)m * 512 + n] = acc[fm][q][r];
            }
        }
}

// ---------------------------------------------------------------- LSTM via MFMA (R10-proven shape), fp16 X, raw barrier
__global__ __launch_bounds__(512) void lstm_mfma(
    const _Float16* __restrict__ X,          // [B,T,128,4] fp16 gate-interleaved
    const __hip_bfloat16* __restrict__ WhT,  // [512][128] bf16
    const float* __restrict__ cin,           // [B,128] or null
    const __hip_bfloat16* __restrict__ hin,  // prev layer out [B,T,128] (t=T-1) or null
    __hip_bfloat16* __restrict__ out,        // [B,T,128] bf16
    float* __restrict__ cf, int initZero)
{
    __shared__ __align__(16) __hip_bfloat16 lh[2][16 * 128];  // double-buffered h matrix
    const int tid = threadIdx.x, l = tid & 63, g = tid >> 6;  // wave 0..7
    const int lr = l & 15, lg = l >> 4;
    const int b0 = blockIdx.x * 4;
    const int j0 = g * 16 + lr;     // hidden column 0..127
    const int hrow = lg * 4;        // A-row for this lane's batch row

    bf16x8 wb[4][4];
    #pragma unroll
    for (int q = 0; q < 4; ++q)
        #pragma unroll
        for (int kf = 0; kf < 4; ++kf)
            wb[q][kf] = *(const bf16x8*)&WhT[(size_t)(q * 128 + g * 16 + lr) * 128 + kf * 32 + lg * 8];

    for (int i = tid; i < 2 * 2048; i += 512) ((__hip_bfloat16*)lh)[i] = __float2bfloat16(0.f);
    __syncthreads();

    float c;
    {
        __hip_bfloat16 h0;
        if (initZero) { c = 0.f; h0 = __float2bfloat16(0.f); }
        else {
            c  = cin[(size_t)(b0 + lg) * 128 + j0];
            h0 = hin[((size_t)(b0 + lg) * T_ + (T_ - 1)) * 128 + j0];
        }
        lh[0][hrow * 128 + ((((j0 >> 3) ^ (hrow & 7)) << 3) | (j0 & 7))] = h0;
    }
    __syncthreads();

    const f16x4* Xl = (const f16x4*)(X + ((size_t)(b0 + lg) * T_) * 512) + j0;
    f16x4 xc = Xl[0];
    f16x4 xn = Xl[128];

    for (int t = 0; t < T_; ++t) {
        f16x4 xn2 = (f16x4){(_Float16)0.f, (_Float16)0.f, (_Float16)0.f, (_Float16)0.f};
        if (t < T_ - 2) xn2 = Xl[(size_t)(t + 2) * 128];
        const int cur = t & 1;
        bf16x8 af[4];
        #pragma unroll
        for (int kf = 0; kf < 4; ++kf) {
            int chunk = (kf * 4 + lg) ^ (lr & 7);
            af[kf] = *(const bf16x8*)&lh[cur][lr * 128 + chunk * 8];
        }
        f32x4 a0 = {0.f,0.f,0.f,0.f}, a1 = {0.f,0.f,0.f,0.f}, a2 = {0.f,0.f,0.f,0.f}, a3 = {0.f,0.f,0.f,0.f};
        #pragma unroll
        for (int kf = 0; kf < 4; ++kf) {
            a0 = __builtin_amdgcn_mfma_f32_16x16x32_bf16(af[kf], wb[0][kf], a0, 0, 0, 0);
            a1 = __builtin_amdgcn_mfma_f32_16x16x32_bf16(af[kf], wb[1][kf], a1, 0, 0, 0);
            a2 = __builtin_amdgcn_mfma_f32_16x16x32_bf16(af[kf], wb[2][kf], a2, 0, 0, 0);
            a3 = __builtin_amdgcn_mfma_f32_16x16x32_bf16(af[kf], wb[3][kf], a3, 0, 0, 0);
        }
        float zi = a0[0] + (float)xc[0];
        float zf = a1[0] + (float)xc[1];
        float zg = a2[0] + (float)xc[2];
        float zo = a3[0] + (float)xc[3];
        float ig = sigfast(zi), fg = sigfast(zf);
        float gg = tanhfast(zg), og = sigfast(zo);
        c = fg * c + ig * gg;
        float h = og * tanhfast(c);
        __hip_bfloat16 hb = __float2bfloat16(h);
        lh[cur ^ 1][hrow * 128 + ((((j0 >> 3) ^ (hrow & 7)) << 3) | (j0 & 7))] = hb;
        out[((size_t)(b0 + lg) * T_ + t) * 128 + j0] = hb;
        lds_barrier();
        xc = xn; xn = xn2;
    }
    cf[(size_t)(b0 + lg) * 128 + j0] = c;
}

// ---------------------------------------------------------------- split-K reduce (64 partials) + bias
__global__ __launch_bounds__(256) void reduce_kernel(
    const float* __restrict__ part, const float* __restrict__ bias,
    float* __restrict__ d)
{
    int i = blockIdx.x * 256 + threadIdx.x;   // 0..131071
    float s = bias[i & 511];
    #pragma unroll
    for (int p = 0; p < 64; ++p) s += part[(size_t)p * 131072 + i];
    d[i] = s;
}

// ---------------------------------------------------------------- BatchNorm (batch stats) + leaky, row-parallel
__global__ __launch_bounds__(256) void bn_kernel(
    float* __restrict__ d, const float* __restrict__ scale, const float* __restrict__ bias)
{
    __shared__ float ss[8][32], ss2[8][32];
    int tid = threadIdx.x;
    int cc = tid & 31, rg = tid >> 5;
    int col = blockIdx.x * 32 + cc;
    float s = 0.f, s2 = 0.f;
    for (int r = rg * 32; r < rg * 32 + 32; ++r) {
        float v = d[(size_t)r * 512 + col];
        s += v; s2 += v * v;
    }
    ss[rg][cc] = s; ss2[rg][cc] = s2;
    __syncthreads();
    float st = 0.f, s2t = 0.f;
    #pragma unroll
    for (int i = 0; i < 8; ++i) { st += ss[i][cc]; s2t += ss2[i][cc]; }
    float mean = st * (1.f / 256.f);
    float var  = s2t * (1.f / 256.f) - mean * mean;
    float inv  = rsqrtf(var + 1e-5f);
    float sc = scale[col] * inv;
    float bi = bias[col] - mean * sc;
    for (int r = rg * 32; r < rg * 32 + 32; ++r) {
        float v = d[(size_t)r * 512 + col] * sc + bi;
        d[(size_t)r * 512 + col] = leakyf(v);
    }
}

// ---------------------------------------------------------------- head GEMV + softmax
__global__ __launch_bounds__(64) void head_kernel(
    const float* __restrict__ d, const float* __restrict__ Wd2,
    const float* __restrict__ bd2, float* __restrict__ out)
{
    int r = blockIdx.x, l = threadIdx.x;
    float acc[10] = {};
    for (int k = l; k < 512; k += 64) {
        float v = d[(size_t)r * 512 + k];
        #pragma unroll
        for (int n = 0; n < 10; ++n) acc[n] += v * Wd2[k * 10 + n];
    }
    #pragma unroll
    for (int n = 0; n < 10; ++n)
        for (int off = 32; off; off >>= 1) acc[n] += __shfl_down(acc[n], off);
    if (l == 0) {
        float mx = -1e30f;
        #pragma unroll
        for (int n = 0; n < 10; ++n) { acc[n] += bd2[n]; mx = fmaxf(mx, acc[n]); }
        float s = 0.f;
        #pragma unroll
        for (int n = 0; n < 10; ++n) { acc[n] = expf(acc[n] - mx); s += acc[n]; }
        float invs = 1.f / s;
        #pragma unroll
        for (int n = 0; n < 10; ++n) out[(size_t)r * 10 + n] = acc[n] * invs;
    }
}

// ----------------------------------------------------------------
extern "C" void kernel_launch(void* const* d_in, const int* in_sizes, int n_in,
                              void* d_out, int out_size, void* d_ws, size_t ws_size,
                              hipStream_t stream)
{
    const float* x   = (const float*)d_in[0];
    const float* W1  = (const float*)d_in[1];
    const float* bc1 = (const float*)d_in[2];
    const float* W2  = (const float*)d_in[3];
    const float* bc2 = (const float*)d_in[4];
    const float* W3  = (const float*)d_in[5];
    const float* bc3 = (const float*)d_in[6];
    const float* Wx1 = (const float*)d_in[7];
    const float* Wh1 = (const float*)d_in[8];
    const float* b1  = (const float*)d_in[9];
    const float* Wx2 = (const float*)d_in[10];
    const float* Wh2 = (const float*)d_in[11];
    const float* b2  = (const float*)d_in[12];
    const float* Wd1 = (const float*)d_in[13];
    const float* bd1 = (const float*)d_in[14];
    const float* bns = (const float*)d_in[15];
    const float* bnb = (const float*)d_in[16];
    const float* Wd2 = (const float*)d_in[17];
    const float* bd2 = (const float*)d_in[18];
    float* outp = (float*)d_out;

    const size_t BT = (size_t)B_ * T_;
    float* ws   = (float*)d_ws;
    float* bufA = ws;                         // BT*512 f (134MB): X(fp16) [0,67MB); a1(bf16) [67,71.2MB);
                                              //   dense partials [0,33.5MB); WdT(bf16) tail [100.7,134MB)
    float* bufC = bufA + BT * 512;            // BT*128 f: out2(bf16)
    float* bufD = bufC + BT * 128;            // BT*128 f: out1(bf16)
    float* bufd = bufD + BT * 128;            // 131072 f
    float* cfb  = bufd + 131072;              // 32768 f
    __hip_bfloat16* WhT1b = (__hip_bfloat16*)(cfb + 32768);
    __hip_bfloat16* WhT2b = WhT1b + 65536;
    __hip_bfloat16* WxT1b = WhT2b + 65536;
    __hip_bfloat16* WxT2b = WxT1b + 65536;
    __hip_bfloat16* W2Tb  = WxT2b + 65536;    // 81920 bf16
    __hip_bfloat16* W3Tb  = W2Tb + 81920;     // 327680 bf16

    __hip_bfloat16* a1b   = (__hip_bfloat16*)(bufA + BT * 256);   // [67, 71.2MB) of bufA
    _Float16*       Xb    = (_Float16*)bufA;                      // [0, 67MB)
    __hip_bfloat16* WdTb  = (__hip_bfloat16*)(bufA + 25165824);   // tail: 16.8M bf16 = 33.5MB
    __hip_bfloat16* out1b = (__hip_bfloat16*)bufD;
    __hip_bfloat16* out2b = (__hip_bfloat16*)bufC;

    // weight preps + conv1 + Wd1 transpose (single dispatch)
    prep_all<<<dim3(14912), dim3(256), 0, stream>>>(Wh1, Wh2, Wx1, Wx2, W2, W3, x, W1, bc1, Wd1,
                                                    WhT1b, WhT2b, WxT1b, WxT2b, W2Tb, W3Tb, a1b, WdTb);

    // conv2+conv3+X1 fused, 64-row tiles: writes X1 (fp16, gate-interleaved) directly
    conv23_fused<<<dim3(B_ * T_ / 64), dim3(512), 0, stream>>>(a1b, W2Tb, bc2, W3Tb, bc3,
                                                               WxT1b, b1, Xb);

    lstm_mfma<<<dim3(64), dim3(512), 0, stream>>>(Xb, WhT1b, nullptr, nullptr, out1b, cfb, 1);
    // X2 = out1 @ Wx2 + b2 (fp16, gate-interleaved coalesced)
    gemm_mfma<<<dim3(512, 1, 1), dim3(512), 0, stream>>>(out1b, WxT2b, b2, (float*)Xb, 128, 128, 1);
    lstm_mfma<<<dim3(64), dim3(512), 0, stream>>>(Xb, WhT2b, cfb, out1b, out2b, cfb, 0);

    // dense: [256, 32768] @ WdT, grid (4 n-tiles x 64 k-chunks) -> 64 partial planes in bufA
    gemm_dense<<<dim3(4, 64), dim3(512), 0, stream>>>(out2b, WdTb, bufA);
    reduce_kernel<<<dim3(512), dim3(256), 0, stream>>>(bufA, bd1, bufd);

    bn_kernel<<<dim3(16), dim3(256), 0, stream>>>(bufd, bns, bnb);
    head_kernel<<<dim3(256), dim3(64), 0, stream>>>(bufd, Wd2, bd2, outp);
}

// Round 17
// 606.299 us; speedup vs baseline: 1.1143x; 1.1143x over previous
//
#include <hip/hip_runtime.h>
#include <hip/hip_bf16.h>
#include <math.h>

#define B_ 256
#define T_ 256
#define HLS 128

typedef __bf16 bf16x8 __attribute__((ext_vector_type(8)));
typedef float f32x4 __attribute__((ext_vector_type(4)));
typedef unsigned int u32x4 __attribute__((ext_vector_type(4)));
typedef _Float16 f16x4 __attribute__((ext_vector_type(4)));

__device__ __forceinline__ float leakyf(float v) { return v > 0.f ? v : 0.01f * v; }
__device__ __forceinline__ float sigfast(float x) { return __builtin_amdgcn_rcpf(1.f + __expf(-x)); }
__device__ __forceinline__ float tanhfast(float x) {
    float e = __expf(2.f * x);
    return 1.f - 2.f * __builtin_amdgcn_rcpf(e + 1.f);
}
__device__ __forceinline__ unsigned short bf16bits(float v) {
    union { __hip_bfloat16 h; unsigned short u; } cv;
    cv.h = __float2bfloat16(v);
    return cv.u;
}
__device__ __forceinline__ unsigned int bfpack(float a, float b) {
    return (unsigned int)bf16bits(a) | ((unsigned int)bf16bits(b) << 16);
}
// barrier that does NOT drain vmcnt: LDS visibility only, global loads stay in flight
__device__ __forceinline__ void lds_barrier() {
    asm volatile("s_waitcnt lgkmcnt(0)" ::: "memory");
    __builtin_amdgcn_s_barrier();
}

// ---------------------------------------------------------------- merged preps + conv1 + Wd1-transpose (one dispatch)
__global__ __launch_bounds__(256) void prep_all(
    const float* __restrict__ Wh1, const float* __restrict__ Wh2,
    const float* __restrict__ Wx1, const float* __restrict__ Wx2,
    const float* __restrict__ W2,  const float* __restrict__ W3,
    const float* __restrict__ x,   const float* __restrict__ W1,
    const float* __restrict__ bc1, const float* __restrict__ Wd1,
    __hip_bfloat16* __restrict__ oh1, __hip_bfloat16* __restrict__ oh2,
    __hip_bfloat16* __restrict__ ox1, __hip_bfloat16* __restrict__ ox2,
    __hip_bfloat16* __restrict__ oW2, __hip_bfloat16* __restrict__ oW3,
    __hip_bfloat16* __restrict__ a1out, __hip_bfloat16* __restrict__ WdT)
{
    __shared__ float tileT[64][68];
    int bx = blockIdx.x;
    if (bx < 1024) {
        int which = bx >> 8;
        int idx = (bx & 255) * 256 + threadIdx.x;   // 0..65535
        int k = idx >> 9, n = idx & 511;
        const float* in = which == 0 ? Wh1 : which == 1 ? Wh2 : which == 2 ? Wx1 : Wx2;
        __hip_bfloat16* out = which == 0 ? oh1 : which == 1 ? oh2 : which == 2 ? ox1 : ox2;
        out[n * 128 + k] = __float2bfloat16(in[idx]);
    } else if (bx < 1344) {
        int idx = (bx - 1024) * 256 + threadIdx.x;  // 0..81919
        int n = idx & 511, r = idx >> 9;
        int ci = r & 31, kt = r >> 5;
        oW2[n * 160 + kt * 32 + ci] = __float2bfloat16(W2[idx]);
    } else if (bx < 2624) {
        int idx = (bx - 1344) * 256 + threadIdx.x;  // 0..327679
        int co = idx & 127, rest = idx >> 7;
        int ci = rest & 511, k = rest >> 9;
        oW3[((size_t)(k * 128 + co)) * 512 + ci] = __float2bfloat16(W3[idx]);
    } else if (bx < 10816) {
        int bb = bx - 2624;                          // 0..8191
        int tid  = threadIdx.x;
        int co   = tid & 31;
        int tsub = tid >> 5;
        int b    = bb >> 5;
        int t    = ((bb & 31) << 3) + tsub;
        float acc = bc1[co];
        #pragma unroll
        for (int k = 0; k < 5; ++k) {
            int tt = t + k - 2;
            if (tt < 0 || tt >= T_) continue;
            const float* xr = x + ((size_t)b * T_ + tt) * 8;
            #pragma unroll
            for (int ci = 0; ci < 8; ++ci)
                acc += xr[ci] * W1[(k * 8 + ci) * 32 + co];
        }
        a1out[((size_t)b * T_ + t) * 32 + co] = __float2bfloat16(leakyf(acc));
    } else {
        int tt = bx - 10816;                         // 0..4095
        int tid = threadIdx.x;
        int k0 = (tt & 511) * 64, n0 = (tt >> 9) * 64;
        #pragma unroll
        for (int it = 0; it < 4; ++it) {
            int idx = tid + it * 256;        // 0..1023
            int k = idx >> 4, nc = idx & 15;
            float4 v = *(const float4*)&Wd1[(size_t)(k0 + k) * 512 + n0 + nc * 4];
            tileT[nc * 4 + 0][k] = v.x; tileT[nc * 4 + 1][k] = v.y;
            tileT[nc * 4 + 2][k] = v.z; tileT[nc * 4 + 3][k] = v.w;
        }
        __syncthreads();
        #pragma unroll
        for (int it = 0; it < 2; ++it) {
            int idx = tid + it * 256;        // 0..511
            int n = idx >> 3, kc = idx & 7;
            const float* src = &tileT[n][kc * 8];
            float4 a = *(const float4*)src;
            float4 b = *(const float4*)(src + 4);
            u32x4 w = { bfpack(a.x, a.y), bfpack(a.z, a.w), bfpack(b.x, b.y), bfpack(b.z, b.w) };
            *(u32x4*)&WdT[(size_t)(n0 + n) * 32768 + k0 + kc * 8] = w;
        }
    }
}

// ---------------------------------------------------------------- FUSED conv2+conv3+X1: [B,T,32]bf16 -> X1 fp16 gate-interleaved
// a2t layout: [row][136] plain — row stride 136 shorts = 17x16B, so the odd stride itself rotates
// bank groups per row (group = (17L + chunk) mod 8 = (lr+lg+const) mod 8, uniform). NO swizzle math.
__global__ __launch_bounds__(512) void conv23_fused(
    const __hip_bfloat16* __restrict__ a1,   // [B*T][32]
    const __hip_bfloat16* __restrict__ W2T,  // [512][160]
    const float* __restrict__ bias2,
    const __hip_bfloat16* __restrict__ W3T,  // [5][128][512]
    const float* __restrict__ bias3,
    const __hip_bfloat16* __restrict__ WxT1, // [512][128]
    const float* __restrict__ b1,
    _Float16* __restrict__ Xout)             // [B,T,128,4] fp16 gate-interleaved
{
    __shared__ __align__(16) unsigned short a1t[148 * 40];
    __shared__ __align__(16) unsigned short a2t[132 * 136];
    const int tid = threadIdx.x, l = tid & 63, w = tid >> 6;
    const int lr = l & 15, lg = l >> 4;
    const int b  = blockIdx.x >> 1;
    const int t0 = (blockIdx.x & 1) << 7;
    const size_t bT = (size_t)b * T_;

    for (int i = tid; i < 148 * 4; i += 512) {
        int row = i >> 2, c = i & 3;
        int t = t0 - 4 + row;
        u32x4 v = {0u, 0u, 0u, 0u};
        if (t >= 0 && t < T_) v = *(const u32x4*)&a1[(bT + t) * 32 + c * 8];
        *(u32x4*)&a1t[row * 40 + c * 8] = v;
    }

    f32x4 acc3[4][2];
    #pragma unroll
    for (int fm = 0; fm < 4; ++fm)
        #pragma unroll
        for (int n = 0; n < 2; ++n) acc3[fm][n] = (f32x4){0.f, 0.f, 0.f, 0.f};

    const int tq = w >> 2, cq = w & 3;
    __syncthreads();

    #pragma unroll 1
    for (int cic = 0; cic < 4; ++cic) {
        {
            const int co2 = cic * 128 + w * 16 + lr;
            bf16x8 bf2[5];
            #pragma unroll
            for (int kt = 0; kt < 5; ++kt)
                bf2[kt] = *(const bf16x8*)&W2T[(size_t)co2 * 160 + kt * 32 + lg * 8];
            const float bb2 = bias2[co2];
            const int colc = w * 16 + lr;            // local a2 column, plain
            #pragma unroll 1
            for (int m = 0; m < 9; ++m) {
                f32x4 a = (f32x4){0.f, 0.f, 0.f, 0.f};
                #pragma unroll
                for (int kt = 0; kt < 5; ++kt) {
                    bf16x8 af = *(const bf16x8*)&a1t[(m * 16 + lr + kt) * 40 + lg * 8];
                    a = __builtin_amdgcn_mfma_f32_16x16x32_bf16(af, bf2[kt], a, 0, 0, 0);
                }
                #pragma unroll
                for (int r = 0; r < 4; ++r) {
                    int L = m * 16 + lg * 4 + r;
                    int t = t0 - 2 + L;
                    unsigned short v = 0;
                    if (t >= 0 && t < T_) v = bf16bits(leakyf(a[r] + bb2));
                    if (L < 132)
                        a2t[L * 136 + colc] = v;
                }
            }
        }
        __syncthreads();
        #pragma unroll 1
        for (int k = 0; k < 5; ++k) {
            #pragma unroll
            for (int cf = 0; cf < 4; ++cf) {
                bf16x8 af3[4];
                #pragma unroll
                for (int fm = 0; fm < 4; ++fm) {
                    int L = tq * 64 + fm * 16 + lr + k;
                    af3[fm] = *(const bf16x8*)&a2t[L * 136 + cf * 32 + lg * 8];
                }
                #pragma unroll
                for (int n = 0; n < 2; ++n) {
                    bf16x8 bf = *(const bf16x8*)&W3T[(size_t)(k * 128 + cq * 32 + n * 16 + lr) * 512
                                                     + cic * 128 + cf * 32 + lg * 8];
                    acc3[0][n] = __builtin_amdgcn_mfma_f32_16x16x32_bf16(af3[0], bf, acc3[0][n], 0, 0, 0);
                    acc3[1][n] = __builtin_amdgcn_mfma_f32_16x16x32_bf16(af3[1], bf, acc3[1][n], 0, 0, 0);
                    acc3[2][n] = __builtin_amdgcn_mfma_f32_16x16x32_bf16(af3[2], bf, acc3[2][n], 0, 0, 0);
                    acc3[3][n] = __builtin_amdgcn_mfma_f32_16x16x32_bf16(af3[3], bf, acc3[3][n], 0, 0, 0);
                }
            }
        }
        __syncthreads();
    }
    // ---- a3 tile (bias+leaky, bf16) into LDS (reuse a2t, plain layout), rows 0..127
    #pragma unroll
    for (int n = 0; n < 2; ++n) {
        int co = cq * 32 + n * 16 + lr;
        float bb = bias3[co];
        #pragma unroll
        for (int fm = 0; fm < 4; ++fm) {
            #pragma unroll
            for (int r = 0; r < 4; ++r) {
                int L = tq * 64 + fm * 16 + lg * 4 + r;
                a2t[L * 136 + co] = bf16bits(leakyf(acc3[fm][n][r] + bb));
            }
        }
    }
    __syncthreads();
    // ---- X1 phase: wave w owns rows w*16..w*16+15, all 512 gate cols, K=128
    const int Lr = w * 16 + lr;
    bf16x8 afx[4];
    #pragma unroll
    for (int kf = 0; kf < 4; ++kf)
        afx[kf] = *(const bf16x8*)&a2t[Lr * 136 + kf * 32 + lg * 8];
    _Float16* X16 = Xout + (bT + t0) * 512;
    #pragma unroll
    for (int hh = 0; hh < 2; ++hh) {
        f32x4 acc2[4][4];
        #pragma unroll
        for (int s = 0; s < 4; ++s)
            #pragma unroll
            for (int qq = 0; qq < 4; ++qq) acc2[s][qq] = (f32x4){0.f, 0.f, 0.f, 0.f};
        #pragma unroll
        for (int s = 0; s < 4; ++s)
            #pragma unroll
            for (int qq = 0; qq < 4; ++qq) {
                int n = s * 128 + hh * 64 + qq * 16 + lr;
                #pragma unroll
                for (int kf = 0; kf < 4; ++kf) {
                    bf16x8 bf = *(const bf16x8*)&WxT1[(size_t)n * 128 + kf * 32 + lg * 8];
                    acc2[s][qq] = __builtin_amdgcn_mfma_f32_16x16x32_bf16(afx[kf], bf, acc2[s][qq], 0, 0, 0);
                }
            }
        #pragma unroll
        for (int qq = 0; qq < 4; ++qq) {
            int j = hh * 64 + qq * 16 + lr;
            float bi = b1[j], bfv = b1[j + 128], bg = b1[j + 256], bo = b1[j + 384];
            #pragma unroll
            for (int r = 0; r < 4; ++r) {
                int m = w * 16 + lg * 4 + r;
                f16x4 v = { (_Float16)(acc2[0][qq][r] + bi), (_Float16)(acc2[1][qq][r] + bfv),
                            (_Float16)(acc2[2][qq][r] + bg), (_Float16)(acc2[3][qq][r] + bo) };
                *(f16x4*)&X16[(size_t)m * 512 + (size_t)j * 4] = v;
            }
        }
    }
}

// ---------------------------------------------------------------- X-GEMM (bf16 MFMA): X[m][j][gate] fp16 = A[M,128] @ BT[512,128]^T + b
__global__ __launch_bounds__(512) void gemm_mfma(
    const __hip_bfloat16* __restrict__ A,
    const __hip_bfloat16* __restrict__ BT,
    const float* __restrict__ bias,
    float* __restrict__ C,
    int K, int klen, int ileave)
{
    const int tid = threadIdx.x, l = tid & 63, w = tid >> 6;
    const int lr = l & 15, lg = l >> 4;
    const size_t m0 = (size_t)blockIdx.x * 128 + w * 16;
    const int k0 = blockIdx.z * klen;
    C += (size_t)blockIdx.z * gridDim.x * 128 * 512;

    f32x4 acc[32];
    #pragma unroll
    for (int q = 0; q < 32; ++q) acc[q] = (f32x4){0.f, 0.f, 0.f, 0.f};

    const __hip_bfloat16* Arow  = A + (m0 + lr) * (size_t)K + k0 + lg * 8;
    const __hip_bfloat16* Bbase = BT + (size_t)lr * K + k0 + lg * 8;

    const int nkf = klen >> 5;
    for (int kf = 0; kf < nkf; ++kf) {
        bf16x8 af = *(const bf16x8*)(Arow + kf * 32);
        #pragma unroll
        for (int q = 0; q < 32; ++q) {
            bf16x8 bf = *(const bf16x8*)(Bbase + (size_t)q * 16 * K + kf * 32);
            acc[q] = __builtin_amdgcn_mfma_f32_16x16x32_bf16(af, bf, acc[q], 0, 0, 0);
        }
    }
    if (ileave) {
        _Float16* C16 = (_Float16*)C;
        #pragma unroll
        for (int qj = 0; qj < 8; ++qj) {
            int j = qj * 16 + lr;
            float bi = bias[j], bf_ = bias[j + 128], bg = bias[j + 256], bo = bias[j + 384];
            #pragma unroll
            for (int r = 0; r < 4; ++r) {
                size_t m = m0 + lg * 4 + r;
                f16x4 v = { (_Float16)(acc[qj][r] + bi), (_Float16)(acc[qj + 8][r] + bf_),
                            (_Float16)(acc[qj + 16][r] + bg), (_Float16)(acc[qj + 24][r] + bo) };
                *(f16x4*)&C16[m * 512 + (size_t)j * 4] = v;
            }
        }
    } else {
        #pragma unroll
        for (int q = 0; q < 32; ++q) {
            int n = q * 16 + lr;
            float bb = bias ? bias[n] : 0.f;
            #pragma unroll
            for (int r = 0; r < 4; ++r) {
                size_t m = m0 + lg * 4 + r;
                C[m * 512 + n] = acc[q][r] + bb;
            }
        }
    }
}

// ---------------------------------------------------------------- dense GEMM: part[z][256][512] = out2[256,32768] @ WdT[512,32768]^T
__global__ __launch_bounds__(512) void gemm_dense(
    const __hip_bfloat16* __restrict__ A,    // [256][32768]
    const __hip_bfloat16* __restrict__ BT,   // [512][32768]
    float* __restrict__ part)                // [64][256][512]
{
    const int tid = threadIdx.x, l = tid & 63, w = tid >> 6;
    const int lr = l & 15, lg = l >> 4;
    const int nt = blockIdx.x;               // 0..3
    const int z  = blockIdx.y;               // 0..63
    const int k0 = z * 512;
    const int m0 = w * 32;

    f32x4 acc[2][8];
    #pragma unroll
    for (int fm = 0; fm < 2; ++fm)
        #pragma unroll
        for (int q = 0; q < 8; ++q) acc[fm][q] = (f32x4){0.f, 0.f, 0.f, 0.f};

    const __hip_bfloat16* Ab = A  + (size_t)(m0 + lr) * 32768 + k0 + lg * 8;
    const __hip_bfloat16* Bb = BT + (size_t)(nt * 128 + lr) * 32768 + k0 + lg * 8;

    #pragma unroll 2
    for (int kf = 0; kf < 16; ++kf) {
        bf16x8 af0 = *(const bf16x8*)(Ab + kf * 32);
        bf16x8 af1 = *(const bf16x8*)(Ab + (size_t)16 * 32768 + kf * 32);
        #pragma unroll
        for (int q = 0; q < 8; ++q) {
            bf16x8 bf = *(const bf16x8*)(Bb + (size_t)q * 16 * 32768 + kf * 32);
            acc[0][q] = __builtin_amdgcn_mfma_f32_16x16x32_bf16(af0, bf, acc[0][q], 0, 0, 0);
            acc[1][q] = __builtin_amdgcn_mfma_f32_16x16x32_bf16(af1, bf, acc[1][q], 0, 0, 0);
        }
    }
    float* Cp = part + (size_t)z * 131072;
    #pragma unroll
    for (int fm = 0; fm < 2; ++fm)
        #pragma unroll
        for (int q = 0; q < 8; ++q) {
            int n = nt * 128 + q * 16 + lr;
            #pragma unroll
            for (int r = 0; r < 4; ++r) {
                int m = m0 + fm * 16 + lg * 4 + r;
                Cp[(size_t)m * 512 + n] = acc[fm][q][r];
            }
        }
}

// ---------------------------------------------------------------- LSTM via MFMA (R10-proven shape), fp16 X, raw barrier
__global__ __launch_bounds__(512) void lstm_mfma(
    const _Float16* __restrict__ X,          // [B,T,128,4] fp16 gate-interleaved
    const __hip_bfloat16* __restrict__ WhT,  // [512][128] bf16
    const float* __restrict__ cin,           // [B,128] or null
    const __hip_bfloat16* __restrict__ hin,  // prev layer out [B,T,128] (t=T-1) or null
    __hip_bfloat16* __restrict__ out,        // [B,T,128] bf16
    float* __restrict__ cf, int initZero)
{
    __shared__ __align__(16) __hip_bfloat16 lh[2][16 * 128];  // double-buffered h matrix
    const int tid = threadIdx.x, l = tid & 63, g = tid >> 6;  // wave 0..7
    const int lr = l & 15, lg = l >> 4;
    const int b0 = blockIdx.x * 4;
    const int j0 = g * 16 + lr;     // hidden column 0..127
    const int hrow = lg * 4;        // A-row for this lane's batch row

    bf16x8 wb[4][4];
    #pragma unroll
    for (int q = 0; q < 4; ++q)
        #pragma unroll
        for (int kf = 0; kf < 4; ++kf)
            wb[q][kf] = *(const bf16x8*)&WhT[(size_t)(q * 128 + g * 16 + lr) * 128 + kf * 32 + lg * 8];

    for (int i = tid; i < 2 * 2048; i += 512) ((__hip_bfloat16*)lh)[i] = __float2bfloat16(0.f);
    __syncthreads();

    float c;
    {
        __hip_bfloat16 h0;
        if (initZero) { c = 0.f; h0 = __float2bfloat16(0.f); }
        else {
            c  = cin[(size_t)(b0 + lg) * 128 + j0];
            h0 = hin[((size_t)(b0 + lg) * T_ + (T_ - 1)) * 128 + j0];
        }
        lh[0][hrow * 128 + ((((j0 >> 3) ^ (hrow & 7)) << 3) | (j0 & 7))] = h0;
    }
    __syncthreads();

    const f16x4* Xl = (const f16x4*)(X + ((size_t)(b0 + lg) * T_) * 512) + j0;
    f16x4 xc = Xl[0];
    f16x4 xn = Xl[128];

    for (int t = 0; t < T_; ++t) {
        f16x4 xn2 = (f16x4){(_Float16)0.f, (_Float16)0.f, (_Float16)0.f, (_Float16)0.f};
        if (t < T_ - 2) xn2 = Xl[(size_t)(t + 2) * 128];
        const int cur = t & 1;
        bf16x8 af[4];
        #pragma unroll
        for (int kf = 0; kf < 4; ++kf) {
            int chunk = (kf * 4 + lg) ^ (lr & 7);
            af[kf] = *(const bf16x8*)&lh[cur][lr * 128 + chunk * 8];
        }
        f32x4 a0 = {0.f,0.f,0.f,0.f}, a1 = {0.f,0.f,0.f,0.f}, a2 = {0.f,0.f,0.f,0.f}, a3 = {0.f,0.f,0.f,0.f};
        #pragma unroll
        for (int kf = 0; kf < 4; ++kf) {
            a0 = __builtin_amdgcn_mfma_f32_16x16x32_bf16(af[kf], wb[0][kf], a0, 0, 0, 0);
            a1 = __builtin_amdgcn_mfma_f32_16x16x32_bf16(af[kf], wb[1][kf], a1, 0, 0, 0);
            a2 = __builtin_amdgcn_mfma_f32_16x16x32_bf16(af[kf], wb[2][kf], a2, 0, 0, 0);
            a3 = __builtin_amdgcn_mfma_f32_16x16x32_bf16(af[kf], wb[3][kf], a3, 0, 0, 0);
        }
        float zi = a0[0] + (float)xc[0];
        float zf = a1[0] + (float)xc[1];
        float zg = a2[0] + (float)xc[2];
        float zo = a3[0] + (float)xc[3];
        float ig = sigfast(zi), fg = sigfast(zf);
        float gg = tanhfast(zg), og = sigfast(zo);
        c = fg * c + ig * gg;
        float h = og * tanhfast(c);
        __hip_bfloat16 hb = __float2bfloat16(h);
        lh[cur ^ 1][hrow * 128 + ((((j0 >> 3) ^ (hrow & 7)) << 3) | (j0 & 7))] = hb;
        out[((size_t)(b0 + lg) * T_ + t) * 128 + j0] = hb;
        lds_barrier();
        xc = xn; xn = xn2;
    }
    cf[(size_t)(b0 + lg) * 128 + j0] = c;
}

// ---------------------------------------------------------------- split-K reduce (64 partials) + bias
__global__ __launch_bounds__(256) void reduce_kernel(
    const float* __restrict__ part, const float* __restrict__ bias,
    float* __restrict__ d)
{
    int i = blockIdx.x * 256 + threadIdx.x;   // 0..131071
    float s = bias[i & 511];
    #pragma unroll
    for (int p = 0; p < 64; ++p) s += part[(size_t)p * 131072 + i];
    d[i] = s;
}

// ---------------------------------------------------------------- BatchNorm (batch stats) + leaky, row-parallel
__global__ __launch_bounds__(256) void bn_kernel(
    float* __restrict__ d, const float* __restrict__ scale, const float* __restrict__ bias)
{
    __shared__ float ss[8][32], ss2[8][32];
    int tid = threadIdx.x;
    int cc = tid & 31, rg = tid >> 5;
    int col = blockIdx.x * 32 + cc;
    float s = 0.f, s2 = 0.f;
    for (int r = rg * 32; r < rg * 32 + 32; ++r) {
        float v = d[(size_t)r * 512 + col];
        s += v; s2 += v * v;
    }
    ss[rg][cc] = s; ss2[rg][cc] = s2;
    __syncthreads();
    float st = 0.f, s2t = 0.f;
    #pragma unroll
    for (int i = 0; i < 8; ++i) { st += ss[i][cc]; s2t += ss2[i][cc]; }
    float mean = st * (1.f / 256.f);
    float var  = s2t * (1.f / 256.f) - mean * mean;
    float inv  = rsqrtf(var + 1e-5f);
    float sc = scale[col] * inv;
    float bi = bias[col] - mean * sc;
    for (int r = rg * 32; r < rg * 32 + 32; ++r) {
        float v = d[(size_t)r * 512 + col] * sc + bi;
        d[(size_t)r * 512 + col] = leakyf(v);
    }
}

// ---------------------------------------------------------------- head GEMV + softmax
__global__ __launch_bounds__(64) void head_kernel(
    const float* __restrict__ d, const float* __restrict__ Wd2,
    const float* __restrict__ bd2, float* __restrict__ out)
{
    int r = blockIdx.x, l = threadIdx.x;
    float acc[10] = {};
    for (int k = l; k < 512; k += 64) {
        float v = d[(size_t)r * 512 + k];
        #pragma unroll
        for (int n = 0; n < 10; ++n) acc[n] += v * Wd2[k * 10 + n];
    }
    #pragma unroll
    for (int n = 0; n < 10; ++n)
        for (int off = 32; off; off >>= 1) acc[n] += __shfl_down(acc[n], off);
    if (l == 0) {
        float mx = -1e30f;
        #pragma unroll
        for (int n = 0; n < 10; ++n) { acc[n] += bd2[n]; mx = fmaxf(mx, acc[n]); }
        float s = 0.f;
        #pragma unroll
        for (int n = 0; n < 10; ++n) { acc[n] = expf(acc[n] - mx); s += acc[n]; }
        float invs = 1.f / s;
        #pragma unroll
        for (int n = 0; n < 10; ++n) out[(size_t)r * 10 + n] = acc[n] * invs;
    }
}

// ----------------------------------------------------------------
extern "C" void kernel_launch(void* const* d_in, const int* in_sizes, int n_in,
                              void* d_out, int out_size, void* d_ws, size_t ws_size,
                              hipStream_t stream)
{
    const float* x   = (const float*)d_in[0];
    const float* W1  = (const float*)d_in[1];
    const float* bc1 = (const float*)d_in[2];
    const float* W2  = (const float*)d_in[3];
    const float* bc2 = (const float*)d_in[4];
    const float* W3  = (const float*)d_in[5];
    const float* bc3 = (const float*)d_in[6];
    const float* Wx1 = (const float*)d_in[7];
    const float* Wh1 = (const float*)d_in[8];
    const float* b1  = (const float*)d_in[9];
    const float* Wx2 = (const float*)d_in[10];
    const float* Wh2 = (const float*)d_in[11];
    const float* b2  = (const float*)d_in[12];
    const float* Wd1 = (const float*)d_in[13];
    const float* bd1 = (const float*)d_in[14];
    const float* bns = (const float*)d_in[15];
    const float* bnb = (const float*)d_in[16];
    const float* Wd2 = (const float*)d_in[17];
    const float* bd2 = (const float*)d_in[18];
    float* outp = (float*)d_out;

    const size_t BT = (size_t)B_ * T_;
    float* ws   = (float*)d_ws;
    float* bufA = ws;                         // BT*512 f (134MB): X(fp16) [0,67MB); a1(bf16) [67,71.2MB);
                                              //   dense partials [0,33.5MB); WdT(bf16) tail [100.7,134MB)
    float* bufC = bufA + BT * 512;            // BT*128 f: out2(bf16)
    float* bufD = bufC + BT * 128;            // BT*128 f: out1(bf16)
    float* bufd = bufD + BT * 128;            // 131072 f
    float* cfb  = bufd + 131072;              // 32768 f
    __hip_bfloat16* WhT1b = (__hip_bfloat16*)(cfb + 32768);
    __hip_bfloat16* WhT2b = WhT1b + 65536;
    __hip_bfloat16* WxT1b = WhT2b + 65536;
    __hip_bfloat16* WxT2b = WxT1b + 65536;
    __hip_bfloat16* W2Tb  = WxT2b + 65536;    // 81920 bf16
    __hip_bfloat16* W3Tb  = W2Tb + 81920;     // 327680 bf16

    __hip_bfloat16* a1b   = (__hip_bfloat16*)(bufA + BT * 256);   // [67, 71.2MB) of bufA
    _Float16*       Xb    = (_Float16*)bufA;                      // [0, 67MB)
    __hip_bfloat16* WdTb  = (__hip_bfloat16*)(bufA + 25165824);   // tail: 16.8M bf16 = 33.5MB
    __hip_bfloat16* out1b = (__hip_bfloat16*)bufD;
    __hip_bfloat16* out2b = (__hip_bfloat16*)bufC;

    // weight preps + conv1 + Wd1 transpose (single dispatch)
    prep_all<<<dim3(14912), dim3(256), 0, stream>>>(Wh1, Wh2, Wx1, Wx2, W2, W3, x, W1, bc1, Wd1,
                                                    WhT1b, WhT2b, WxT1b, WxT2b, W2Tb, W3Tb, a1b, WdTb);

    // conv2+conv3+X1 fused: writes X1 (fp16, gate-interleaved) directly — a2, a3 never in HBM
    conv23_fused<<<dim3(B_ * T_ / 128), dim3(512), 0, stream>>>(a1b, W2Tb, bc2, W3Tb, bc3,
                                                                WxT1b, b1, Xb);

    lstm_mfma<<<dim3(64), dim3(512), 0, stream>>>(Xb, WhT1b, nullptr, nullptr, out1b, cfb, 1);
    // X2 = out1 @ Wx2 + b2 (fp16, gate-interleaved coalesced)
    gemm_mfma<<<dim3(512, 1, 1), dim3(512), 0, stream>>>(out1b, WxT2b, b2, (float*)Xb, 128, 128, 1);
    lstm_mfma<<<dim3(64), dim3(512), 0, stream>>>(Xb, WhT2b, cfb, out1b, out2b, cfb, 0);

    // dense: [256, 32768] @ WdT, grid (4 n-tiles x 64 k-chunks) -> 64 partial planes in bufA
    gemm_dense<<<dim3(4, 64), dim3(512), 0, stream>>>(out2b, WdTb, bufA);
    reduce_kernel<<<dim3(512), dim3(256), 0, stream>>>(bufA, bd1, bufd);

    bn_kernel<<<dim3(16), dim3(256), 0, stream>>>(bufd, bns, bnb);
    head_kernel<<<dim3(256), dim3(64), 0, stream>>>(bufd, Wd2, bd2, outp);
}